// Round 1
// 312.129 us; speedup vs baseline: 1.0544x; 1.0544x over previous
//
#include <hip/hip_runtime.h>
#include <hip/hip_bf16.h>
#include <cstdint>
#include <cstddef>

#define EPSBN 1e-5f

typedef unsigned short u16;
typedef unsigned int u32;
typedef _Float16 f16;
typedef _Float16 f16x8 __attribute__((ext_vector_type(8)));
typedef float f32x4 __attribute__((ext_vector_type(4)));

// async global->LDS, 16B per lane
__device__ __forceinline__ void async_copy16(void* lds, const void* g) {
    __builtin_amdgcn_global_load_lds(
        (const __attribute__((address_space(1))) u32*)g,
        (__attribute__((address_space(3))) u32*)lds, 16, 0, 0);
}

// ---------------------------------------------------------------------------
// One prep kernel:
//  blocks [0,4352): NCHW f32 -> NHWC f16 transpose (search + kernel acts)
//  blocks [4352,...): weight fragment packing, f16:
//    Bp[oct][k32][lane][j] = W[oct*16+(lane&15)][k32*32+(lane>>4)*8+j]
//    3x3 convs use k = pos*256+cin (matches A im2col order).
//    ranges (blocks): wk 2304 | ws 2304 | wd 768 | wh1 256 | wh2 128
// ---------------------------------------------------------------------------
__global__ __launch_bounds__(256) void prep_all(
    const float* __restrict__ sin, f16* __restrict__ sa,
    const float* __restrict__ kin, f16* __restrict__ ka,
    const float* __restrict__ wk, const float* __restrict__ ws,
    const float* __restrict__ wd, const float* __restrict__ wh1,
    const float* __restrict__ wh2, f16* __restrict__ bpk,
    f16* __restrict__ bps, f16* __restrict__ bpd, f16* __restrict__ bp1,
    f16* __restrict__ bp2) {
    __shared__ float tile[64][65];
    int t = blockIdx.x;
    int tid = threadIdx.x;
    if (t < 4352) {  // 64 b x 4 ctiles x 17 z
        int b = t / 68;
        int rem = t - b * 68;
        int c0 = (rem / 17) * 64;
        int z = rem % 17;
        bool isk = (z == 16);
        const float* in = isk ? kin : sin;
        f16* op = isk ? ka : sa;
        int HW = isk ? 49 : 961;
        int h0 = isk ? 0 : z * 64;
        int cl = tid >> 6;
        int hl = tid & 63;
        for (int r = cl; r < 64; r += 4) {
            int hw = h0 + hl;
            tile[r][hl] =
                (hw < HW) ? in[(size_t)(b * 256 + c0 + r) * HW + hw] : 0.f;
        }
        __syncthreads();
        int c = tid & 63;
        for (int r = cl; r < 64; r += 4) {
            int hw = h0 + r;
            if (hw < HW)
                op[((size_t)b * HW + hw) * 256 + c0 + c] = (f16)tile[c][r];
        }
        return;
    }
    int blk = t - 4352;
    const float* W;
    f16* Bp;
    int nK32, OCr, K, i;
    bool conv = false;
    if (blk < 2304) {
        W = wk; Bp = bpk; nK32 = 72; OCr = 256; K = 2304; conv = true;
        i = blk * 256 + tid;
    } else if (blk < 4608) {
        W = ws; Bp = bps; nK32 = 72; OCr = 256; K = 2304; conv = true;
        i = (blk - 2304) * 256 + tid;
    } else if (blk < 5376) {  // wd: 16 octs * 24 k32 * 512 = 768 blocks
        W = wd; Bp = bpd; nK32 = 24; OCr = 256; K = 768;
        i = (blk - 4608) * 256 + tid;
    } else if (blk < 5632) {
        W = wh1; Bp = bp1; nK32 = 8; OCr = 256; K = 256;
        i = (blk - 5376) * 256 + tid;
    } else {
        W = wh2; Bp = bp2; nK32 = 8; OCr = 10; K = 256;
        i = (blk - 5632) * 256 + tid;
    }
    int per = nK32 * 512;
    int oct = i / per;
    int r = i - oct * per;
    int k32 = r >> 9;
    int lr = r & 511;
    int l = lr >> 3, j = lr & 7;
    int oc = oct * 16 + (l & 15);
    int k = k32 * 32 + ((l >> 4) << 3) + j;
    float v = 0.f;
    if (oc < OCr)
        v = conv ? W[(size_t)(oc * 256 + (k & 255)) * 9 + (k >> 8)]
                 : W[(size_t)oc * K + k];
    Bp[(size_t)(oct * nK32 + k32) * 512 + lr] = (f16)v;
}

// ---------------------------------------------------------------------------
// 8-phase 256x256 f16 MFMA GEMM (learn_hip m201-style schedule, plain HIP).
//  512 thr = 8 waves (2M x 4N), per-wave 128x64 out (8x4 frags 16x16x32).
//  BK=64; LDS 128KB: A 2x32KB (XOR-chunk swizzled, qm-halves contiguous via
//  bit6<->bit7 row remap baked into per-lane stage src) + B 2x32KB (prepacked
//  fragment image, per-lane src / linear dest).
//  Per iteration (2 K-tiles): 8 phases of {ds_read subtile | stage 1
//  half-tile | barrier | lgkmcnt(0) | setprio(1) 16xMFMA setprio(0) |
//  [vmcnt(6) at ph3/ph7] | barrier}.  Stages stay 3 half-tiles ahead;
//  vmcnt never drains to 0 in steady state.  nKt must be even >= 4.
// EPI: 1 BN->f16 NHWC; 2 BN+ReLU->f16 NHWC; 3 +bias->f32 NCHW.
// ---------------------------------------------------------------------------
template <int KHW, int EPI>
__device__ __forceinline__ void gemm8_body(
    f16* lds, const f16* __restrict__ A, const f16* __restrict__ Bp,
    const float* __restrict__ bnp, float* __restrict__ outF,
    f16* __restrict__ oF, int m0, int M, int OC, int C, int H, int W,
    int OH, int OW) {
    const int Ktot = KHW * C;
    const int nKt = Ktot >> 6;  // 64-wide K tiles (even)
    const int nI = nKt >> 1;
    const int nK32 = Ktot >> 5;
    const int tid = threadIdx.x;
    const int lane = tid & 63;
    const int wid = tid >> 6;   // 0..7
    const int rowl = lane & 15;
    const int quad = lane >> 4;
    const int wm = wid >> 2;    // 0..1 (M)
    const int wn = wid & 3;     // 0..3 (N)
    const int OHW = OH * OW;

    // A stage source offsets [h][s]: LDS slot-row = h*128+wid*16+s*8+(lane>>3)
    // global local-row = slot-row with bits 6,7 swapped (qm-half remap);
    // chunk swizzle: src k-chunk = (lane&7) ^ (lane>>3).
    int arow[4];
#pragma unroll
    for (int h = 0; h < 2; ++h)
#pragma unroll
        for (int s = 0; s < 2; ++s) {
            int ml = ((wid & 4) << 5) + h * 64 + (wid & 3) * 16 + s * 8 +
                     (lane >> 3);
            int m = m0 + ml;
            if (m >= M) m = M - 1;
            int b = m / OHW;
            int r = m - b * OHW;
            int y = r / OW;
            int x = r - y * OW;
            arow[h * 2 + s] = ((b * H + y) * W + x) * C +
                              (((lane & 7) ^ (lane >> 3)) << 3);
        }
    // B stage source bases [h]: oct slot = qn*8+wn*2+jj; inverse o(slot).
    int bsrcb[2];
#pragma unroll
    for (int h = 0; h < 2; ++h) {
        int slot = h * 8 + wid;
        int o = ((slot >> 1) & 3) * 4 + ((slot >> 3) << 1) + (slot & 1);
        bsrcb[h] = o * nK32 * 512 + lane * 8;
    }

    auto koff_of = [&](int kt) {
        if (KHW == 9) {
            int pos = kt >> 2;
            int ky = pos / 3, kx = pos - ky * 3;
            return (ky * W + kx) * C + ((kt & 3) << 6);
        }
        return kt << 6;
    };
    auto stageA = [&](int buf, int h, int kt) {
        int koff = koff_of(kt);
#pragma unroll
        for (int s = 0; s < 2; ++s)
            async_copy16(
                &lds[buf * 16384 +
                     ((h * 1024 + wid * 128 + s * 64 + lane) << 3)],
                A + arow[h * 2 + s] + koff);
    };
    auto stageB = [&](int buf, int h, int kt) {
#pragma unroll
        for (int s = 0; s < 2; ++s)
            async_copy16(
                &lds[32768 + buf * 16384 +
                     ((((h * 8 + wid) * 2 + s) * 64 + lane) << 3)],
                Bp + bsrcb[h] + (kt * 2 + s) * 512);
    };

    f32x4 acc[8][4];
#pragma unroll
    for (int i = 0; i < 8; ++i)
#pragma unroll
        for (int j = 0; j < 4; ++j) acc[i][j] = (f32x4)0.f;

    f16x8 ah[4][2], bhA[2][2], bhB[2][2];

    auto dsA = [&](int buf, int qm) {
#pragma unroll
        for (int ii = 0; ii < 4; ++ii) {
            int g = qm * 128 + wm * 64 + ii * 16 + rowl;
#pragma unroll
            for (int ks = 0; ks < 2; ++ks)
                ah[ii][ks] = *(const f16x8*)&lds[
                    buf * 16384 + g * 64 +
                    ((((ks << 2) | quad) ^ (rowl & 7)) << 3)];
        }
    };
    auto dsB = [&](int buf, int qn, f16x8 (&bh)[2][2]) {
#pragma unroll
        for (int jj = 0; jj < 2; ++jj) {
            int slot = qn * 8 + wn * 2 + jj;
#pragma unroll
            for (int ks = 0; ks < 2; ++ks)
                bh[jj][ks] = *(const f16x8*)&lds[
                    32768 + buf * 16384 + (slot * 2 + ks) * 512 + lane * 8];
        }
    };

#define MFMA_QUAD(qm, qn, bh)                                            \
    do {                                                                 \
        _Pragma("unroll") for (int ks = 0; ks < 2; ++ks)                 \
            _Pragma("unroll") for (int ii = 0; ii < 4; ++ii)             \
                _Pragma("unroll") for (int jj = 0; jj < 2; ++jj)         \
                    acc[(qm)*4 + ii][(qn)*2 + jj] =                      \
                        __builtin_amdgcn_mfma_f32_16x16x32_f16(          \
                            ah[ii][ks], bh[jj][ks],                      \
                            acc[(qm)*4 + ii][(qn)*2 + jj], 0, 0, 0);     \
    } while (0)

#define PH_TAIL(MF)                                        \
    __builtin_amdgcn_s_barrier();                          \
    asm volatile("s_waitcnt lgkmcnt(0)" ::: "memory");     \
    __builtin_amdgcn_s_setprio(1);                         \
    MF;                                                    \
    __builtin_amdgcn_s_setprio(0)

    // Prologue: tile0 (4 halves, buf0) + tile1 (Ah0,Bh0,Bh1; buf1).
    // tile1.Ah1 is staged at iteration 0 phase 0 (its steady-state slot).
    stageA(0, 0, 0);
    stageA(0, 1, 0);
    stageB(0, 0, 0);
    stageB(0, 1, 0);
    stageA(1, 0, 1);
    stageB(1, 0, 1);
    stageB(1, 1, 1);
    asm volatile("s_waitcnt vmcnt(6)" ::: "memory");  // tile0 landed
    __builtin_amdgcn_s_barrier();

    for (int it = 0; it < nI; ++it) {
        const bool more = (it + 1 < nI);
        const int t2 = 2 * it + 2;
        const int t3 = 2 * it + 3;
        // ph0: quad(0,0) buf0 | stage buf1.Ah1 <- tile 2it+1
        dsA(0, 0);
        dsB(0, 0, bhA);
        stageA(1, 1, 2 * it + 1);
        PH_TAIL(MFMA_QUAD(0, 0, bhA));
        __builtin_amdgcn_s_barrier();
        // ph1: quad(0,1) buf0 | stage buf0.Ah0 <- t2
        dsB(0, 1, bhB);
        if (more) stageA(0, 0, t2);
        PH_TAIL(MFMA_QUAD(0, 1, bhB));
        __builtin_amdgcn_s_barrier();
        // ph2: quad(1,0) buf0 | stage buf0.Bh0 <- t2
        dsA(0, 1);
        if (more) stageB(0, 0, t2);
        PH_TAIL(MFMA_QUAD(1, 0, bhA));
        __builtin_amdgcn_s_barrier();
        // ph3: quad(1,1) buf0 | stage buf0.Bh1 <- t2 | vmcnt
        if (more) stageB(0, 1, t2);
        PH_TAIL(MFMA_QUAD(1, 1, bhB));
        if (more)
            asm volatile("s_waitcnt vmcnt(6)" ::: "memory");
        else
            asm volatile("s_waitcnt vmcnt(0)" ::: "memory");
        __builtin_amdgcn_s_barrier();
        // ph4: quad(0,0) buf1 | stage buf0.Ah1 <- t2
        dsA(1, 0);
        dsB(1, 0, bhA);
        if (more) stageA(0, 1, t2);
        PH_TAIL(MFMA_QUAD(0, 0, bhA));
        __builtin_amdgcn_s_barrier();
        // ph5: quad(0,1) buf1 | stage buf1.Ah0 <- t3
        dsB(1, 1, bhB);
        if (more) stageA(1, 0, t3);
        PH_TAIL(MFMA_QUAD(0, 1, bhB));
        __builtin_amdgcn_s_barrier();
        // ph6: quad(1,0) buf1 | stage buf1.Bh0 <- t3
        dsA(1, 1);
        if (more) stageB(1, 0, t3);
        PH_TAIL(MFMA_QUAD(1, 0, bhA));
        __builtin_amdgcn_s_barrier();
        // ph7: quad(1,1) buf1 | stage buf1.Bh1 <- t3 | vmcnt
        if (more) stageB(1, 1, t3);
        PH_TAIL(MFMA_QUAD(1, 1, bhB));
        if (more) asm volatile("s_waitcnt vmcnt(6)" ::: "memory");
        __builtin_amdgcn_s_barrier();
    }
#undef PH_TAIL
#undef MFMA_QUAD

    // Epilogue. C/D layout: col(n) = lane&15, row(m) = quad*4 + reg.
#pragma unroll
    for (int j = 0; j < 4; ++j) {
        int oc = wn * 64 + j * 16 + rowl;
        bool ocv = oc < OC;
        float scale = 1.f, shift = 0.f;
        if (ocv) {
            if (EPI != 3) {
                float g = bnp[oc];
                float bb = bnp[OC + oc];
                float mm = bnp[2 * OC + oc];
                float vv = bnp[3 * OC + oc];
                float inv = g * rsqrtf(vv + EPSBN);
                scale = inv;
                shift = bb - mm * inv;
            } else {
                shift = bnp[oc];  // bias
            }
        }
#pragma unroll
        for (int i = 0; i < 8; ++i) {
#pragma unroll
            for (int r = 0; r < 4; ++r) {
                int m = m0 + wm * 128 + i * 16 + quad * 4 + r;
                if (m < M && ocv) {
                    float v = acc[i][j][r] * scale + shift;
                    if (EPI == 2) v = fmaxf(v, 0.f);
                    if (EPI == 3) {
                        int b = m / OHW;
                        int rr = m - b * OHW;
                        outF[((size_t)b * OC + oc) * OHW + rr] = v;
                    } else {
                        oF[(size_t)m * OC + oc] = (f16)v;
                    }
                }
            }
        }
    }
}

// Fused conv3x3, 8-phase: kernel branch first (blocks [0,7)), search [7,218).
__global__ __launch_bounds__(512, 2) void conv33_fused8(
    const f16* sA_g, const f16* bpS, const float* bns, f16* sOut,
    const f16* kA_g, const f16* bpK, const float* bnk, f16* kOut) {
    __shared__ f16 lds[65536];  // 128 KB
    bool sec = blockIdx.x < 7;
    const f16* A = sec ? kA_g : sA_g;
    const f16* Bp = sec ? bpK : bpS;
    const float* bnp = sec ? bnk : bns;
    f16* oF = sec ? kOut : sOut;
    int M = sec ? 1600 : 53824;
    int Hh = sec ? 7 : 31;
    int OHs = sec ? 5 : 29;
    int m0 = (sec ? blockIdx.x : (blockIdx.x - 7)) * 256;
    gemm8_body<9, 2>(lds, A, Bp, bnp, nullptr, oF, m0, M, 256, 256, Hh, Hh,
                     OHs, OHs);
}

// ---------------------------------------------------------------------------
// f16 MFMA GEMM, double-buffered (2-phase) — used by the 1x1 layers.
// BM=BN=128, 256 thr, 4 waves (2m x 2n), each 64x64 via 4x4 16x16x32 MFMA.
// ---------------------------------------------------------------------------
template <int KHW, int EPI>
__device__ __forceinline__ void gemm_body(
    f16* sA, const f16* __restrict__ A, const f16* __restrict__ Bp,
    const float* __restrict__ bnp, float* __restrict__ outF,
    f16* __restrict__ oF, int m0, int n0, int M, int OC, int C, int H, int W,
    int OH, int OW) {
    const int Ktot = KHW * C;
    const int nKb = Ktot >> 7;   // 128-wide K windows (even)
    const int nK32 = Ktot >> 5;  // Bp granularity
    const int tid = threadIdx.x;
    const int OHW = OH * OW;

    int abase[8];
#pragma unroll
    for (int s = 0; s < 8; ++s) {
        int idx = tid + s * 256;
        int ml = idx >> 4;
        int qs = (idx & 15) ^ (ml & 15);
        int m = m0 + ml;
        if (m >= M) m = M - 1;
        int b = m / OHW;
        int r = m - b * OHW;
        int y = r / OW;
        int x = r - y * OW;
        abase[s] = ((b * H + y) * W + x) * C + qs * 8;
    }

    f32x4 acc[4][4];
#pragma unroll
    for (int i = 0; i < 4; ++i)
#pragma unroll
        for (int j = 0; j < 4; ++j) acc[i][j] = (f32x4)0.f;

    const int lane = tid & 63;
    const int row = lane & 15;
    const int quad = lane >> 4;
    const int wv = tid >> 6;
    const int wm = (wv & 1) * 64;
    const int wn = (wv >> 1) * 64;
    const int octb = (n0 + wn) >> 4;

    auto koff_of = [&](int kb) {
        if (KHW == 9) {
            int pos = kb >> 1;
            int cin0 = (kb & 1) << 7;
            int ky = pos / 3;
            int kx = pos - ky * 3;
            return (ky * W + kx) * C + cin0;
        }
        return kb << 7;
    };
    auto issueA = [&](int bufbase, int kb) {
        int koff = koff_of(kb);
#pragma unroll
        for (int s = 0; s < 8; ++s)
            async_copy16(&sA[bufbase + tid * 8 + s * 2048],
                         A + abase[s] + koff);
    };
    auto loadB = [&](f16x8(&bh)[4][4], int kb) {
#pragma unroll
        for (int ks = 0; ks < 4; ++ks)
#pragma unroll
            for (int j = 0; j < 4; ++j)
                bh[ks][j] =
                    *(const f16x8*)&Bp[((size_t)(octb + j) * nK32 + kb * 4 +
                                        ks) *
                                           512 +
                                       lane * 8];
    };
    auto compute = [&](int bufbase, f16x8(&bh)[4][4]) {
#pragma unroll
        for (int ks = 0; ks < 4; ++ks) {
            f16x8 ah[4];
#pragma unroll
            for (int i = 0; i < 4; ++i) {
                int g = wm + i * 16 + row;
                ah[i] = *(const f16x8*)&sA[bufbase + g * 128 +
                                           ((((ks << 2) | quad) ^ row) << 3)];
            }
#pragma unroll
            for (int i = 0; i < 4; ++i)
#pragma unroll
                for (int j = 0; j < 4; ++j)
                    acc[i][j] = __builtin_amdgcn_mfma_f32_16x16x32_f16(
                        ah[i], bh[ks][j], acc[i][j], 0, 0, 0);
        }
    };

    f16x8 bh0[4][4], bh1[4][4];
    issueA(0, 0);
    loadB(bh0, 0);
    for (int kb = 0; kb < nKb; kb += 2) {
        __syncthreads();
        issueA(16384, kb + 1);
        loadB(bh1, kb + 1);
        compute(0, bh0);
        __syncthreads();
        if (kb + 2 < nKb) {
            issueA(0, kb + 2);
            loadB(bh0, kb + 2);
        }
        compute(16384, bh1);
    }

#pragma unroll
    for (int j = 0; j < 4; ++j) {
        int oc = n0 + wn + j * 16 + row;
        bool ocv = oc < OC;
        float scale = 1.f, shift = 0.f;
        if (ocv) {
            if (EPI != 3) {
                float g = bnp[oc];
                float bb = bnp[OC + oc];
                float mm = bnp[2 * OC + oc];
                float vv = bnp[3 * OC + oc];
                float inv = g * rsqrtf(vv + EPSBN);
                scale = inv;
                shift = bb - mm * inv;
            } else {
                shift = bnp[oc];  // bias
            }
        }
#pragma unroll
        for (int i = 0; i < 4; ++i) {
#pragma unroll
            for (int r = 0; r < 4; ++r) {
                int m = m0 + wm + i * 16 + quad * 4 + r;
                if (m < M && ocv) {
                    float v = acc[i][j][r] * scale + shift;
                    if (EPI == 2) v = fmaxf(v, 0.f);
                    if (EPI == 3) {
                        int b = m / OHW;
                        int rr = m - b * OHW;
                        outF[((size_t)b * OC + oc) * OHW + rr] = v;
                    } else {
                        oF[(size_t)m * OC + oc] = (f16)v;
                    }
                }
            }
        }
    }
}

template <int EPI>
__global__ __launch_bounds__(256, 2) void gemm_1x1(
    const f16* __restrict__ A, const f16* __restrict__ Bp,
    const float* __restrict__ bnp, float* __restrict__ outF,
    f16* __restrict__ oF, int M, int OC, int C) {
    __shared__ f16 sA[32768];
    gemm_body<1, EPI>(sA, A, Bp, bnp, outF, oF, blockIdx.x * 128,
                      blockIdx.y * 128, M, OC, C, 25, 25, 25, 25);
}

// ---------------------------------------------------------------------------
// Multi-scale depthwise xcorr, NHWC f16 in, f16 NHWC out (f32 accumulate).
// ---------------------------------------------------------------------------
__global__ __launch_bounds__(256) void xcorr_nhwc(
    const f16* __restrict__ sf, const f16* __restrict__ kf,
    f16* __restrict__ feat) {
    int by = blockIdx.x;  // b*25 + y
    int b = by / 25;
    int y = by - b * 25;
    int c = threadIdx.x;  // 0..255
    float kv[25];
#pragma unroll
    for (int p = 0; p < 25; ++p)
        kv[p] = (float)kf[(size_t)(b * 25 + p) * 256 + c];
    const f16* srow = sf + (size_t)(b * 29 + y) * 29 * 256 + c;
    float sv[25];
#pragma unroll
    for (int d = 0; d < 5; ++d)
#pragma unroll
        for (int e = 0; e < 5; ++e)
            sv[d * 5 + e] = (float)srow[(size_t)(d * 29 + e) * 256];
    for (int x = 0;; ++x) {
        float a0 = 0.f, a1 = 0.f, a2;
#pragma unroll
        for (int p = 0; p < 25; ++p) a0 = fmaf(sv[p], kv[p], a0);
#pragma unroll
        for (int d = 1; d < 4; ++d)
#pragma unroll
            for (int e = 1; e < 4; ++e)
                a1 = fmaf(sv[d * 5 + e], kv[d * 5 + e], a1);
        a2 = sv[12] * kv[12];
        size_t o = ((size_t)by * 25 + x) * 768 + c;
        feat[o] = (f16)a0;
        feat[o + 256] = (f16)a1;
        feat[o + 512] = (f16)a2;
        if (x == 24) break;
#pragma unroll
        for (int d = 0; d < 5; ++d) {
#pragma unroll
            for (int e = 0; e < 4; ++e) sv[d * 5 + e] = sv[d * 5 + e + 1];
            sv[d * 5 + 4] = (float)srow[(size_t)(d * 29 + x + 5) * 256];
        }
    }
}

// ---------------------------------------------------------------------------
extern "C" void kernel_launch(void* const* d_in, const int* in_sizes, int n_in,
                              void* d_out, int out_size, void* d_ws,
                              size_t ws_size, hipStream_t stream) {
    const float* kernel_in = (const float*)d_in[0];  // (64,256,7,7)
    const float* search_in = (const float*)d_in[1];  // (64,256,31,31)
    const float* wk = (const float*)d_in[2];         // (256,256,3,3)
    const float* bnk = (const float*)d_in[3];
    const float* ws = (const float*)d_in[4];
    const float* bns = (const float*)d_in[5];
    const float* wd = (const float*)d_in[6];  // (256,768)
    const float* bnd = (const float*)d_in[7];
    const float* wh1 = (const float*)d_in[8];  // (256,256)
    const float* bnh = (const float*)d_in[9];
    const float* wh2 = (const float*)d_in[10];  // (10,256)
    const float* bh2 = (const float*)d_in[11];  // (10,)
    float* out = (float*)d_out;                 // (64,10,25,25) NCHW

    char* base = (char*)d_ws;
    size_t off = 0;
    auto alloc = [&](size_t bytes) {
        off = (off + 511) & ~(size_t)511;
        void* p = base + off;
        off += bytes;
        return p;
    };

    // Persistent region
    f16* bpd = (f16*)alloc((size_t)16 * 24 * 512 * 2);  // wd frags
    f16* bp1 = (f16*)alloc((size_t)16 * 8 * 512 * 2);   // wh1 frags
    f16* bp2 = (f16*)alloc((size_t)8 * 8 * 512 * 2);    // wh2 frags (padded)
    size_t Pf = (off + 511) & ~(size_t)511;  // f2 aliases here later
    f16* kfeat = (f16*)alloc((size_t)1600 * 256 * 2);
    f16* sfeat = (f16*)alloc((size_t)53824 * 256 * 2);
    size_t P1 = (off + 511) & ~(size_t)511;  // feat/hbuf alias here
    // Transients (dead after conv33_fused8)
    f16* bpk = (f16*)alloc((size_t)16 * 72 * 512 * 2);
    f16* bps = (f16*)alloc((size_t)16 * 72 * 512 * 2);
    f16* ka = (f16*)alloc((size_t)64 * 49 * 256 * 2);
    f16* sa = (f16*)alloc((size_t)64 * 961 * 256 * 2);
    // Aliases
    f16* feat = (f16*)(base + P1);  // 40000*768 (over dead transients+free)
    f16* f2 = (f16*)(base + Pf);    // 40000*256 (kfeat/sfeat dead)
    f16* hb = (f16*)(base + P1);    // 40000*256 (feat dead)

    // 1) activation transpose->f16 NHWC + all weight fragment packs
    prep_all<<<dim3(10112), 256, 0, stream>>>(search_in, sa, kernel_in, ka,
                                              wk, ws, wd, wh1, wh2, bpk, bps,
                                              bpd, bp1, bp2);
    // 2) fused conv3x3 (kernel + search), 8-phase 256^2 -> f16 NHWC
    conv33_fused8<<<dim3(218), 512, 0, stream>>>(sa, bps, bns, sfeat, ka,
                                                 bpk, bnk, kfeat);
    // 3) xcorr -> feat f16 NHWC [40000][768]
    xcorr_nhwc<<<dim3(1600), 256, 0, stream>>>(sfeat, kfeat, feat);
    // 4) wd: 1x1, K=768, BN -> f2 f16
    gemm_1x1<1><<<dim3(313, 2), 256, 0, stream>>>(feat, bpd, bnd, nullptr, f2,
                                                  40000, 256, 768);
    // 5) wh1: 1x1, K=256, BN+ReLU -> hb f16
    gemm_1x1<2><<<dim3(313, 2), 256, 0, stream>>>(f2, bp1, bnh, nullptr, hb,
                                                  40000, 256, 256);
    // 6) wh2: 1x1, K=256, +bias -> out f32 NCHW
    gemm_1x1<3><<<dim3(313, 1), 256, 0, stream>>>(hb, bp2, bh2, out, nullptr,
                                                  40000, 10, 256);
}

// Round 3
// 273.330 us; speedup vs baseline: 1.2041x; 1.1420x over previous
//
#include <hip/hip_runtime.h>
#include <hip/hip_bf16.h>
#include <cstdint>
#include <cstddef>

#define EPSBN 1e-5f

typedef unsigned short u16;
typedef unsigned int u32;
typedef _Float16 f16;
typedef _Float16 f16x8 __attribute__((ext_vector_type(8)));
typedef float f32x4 __attribute__((ext_vector_type(4)));

// async global->LDS, 16B per lane
__device__ __forceinline__ void async_copy16(void* lds, const void* g) {
    __builtin_amdgcn_global_load_lds(
        (const __attribute__((address_space(1))) u32*)g,
        (__attribute__((address_space(3))) u32*)lds, 16, 0, 0);
}

// ---------------------------------------------------------------------------
// One prep kernel:
//  blocks [0,4352): NCHW f32 -> NHWC f16 transpose (search + kernel acts)
//  blocks [4352,...): weight fragment packing, f16:
//    Bp[oct][k32][lane][j] = W[oct*16+(lane&15)][k32*32+(lane>>4)*8+j]
//    3x3 convs use k = pos*256+cin (matches A im2col order).
//    ranges (blocks): wk 2304 | ws 2304 | wd 768 | wh1 256 | wh2 128
// ---------------------------------------------------------------------------
__global__ __launch_bounds__(256) void prep_all(
    const float* __restrict__ sin, f16* __restrict__ sa,
    const float* __restrict__ kin, f16* __restrict__ ka,
    const float* __restrict__ wk, const float* __restrict__ ws,
    const float* __restrict__ wd, const float* __restrict__ wh1,
    const float* __restrict__ wh2, f16* __restrict__ bpk,
    f16* __restrict__ bps, f16* __restrict__ bpd, f16* __restrict__ bp1,
    f16* __restrict__ bp2) {
    __shared__ float tile[64][65];
    int t = blockIdx.x;
    int tid = threadIdx.x;
    if (t < 4352) {  // 64 b x 4 ctiles x 17 z
        int b = t / 68;
        int rem = t - b * 68;
        int c0 = (rem / 17) * 64;
        int z = rem % 17;
        bool isk = (z == 16);
        const float* in = isk ? kin : sin;
        f16* op = isk ? ka : sa;
        int HW = isk ? 49 : 961;
        int h0 = isk ? 0 : z * 64;
        int cl = tid >> 6;
        int hl = tid & 63;
        for (int r = cl; r < 64; r += 4) {
            int hw = h0 + hl;
            tile[r][hl] =
                (hw < HW) ? in[(size_t)(b * 256 + c0 + r) * HW + hw] : 0.f;
        }
        __syncthreads();
        int c = tid & 63;
        for (int r = cl; r < 64; r += 4) {
            int hw = h0 + r;
            if (hw < HW)
                op[((size_t)b * HW + hw) * 256 + c0 + c] = (f16)tile[c][r];
        }
        return;
    }
    int blk = t - 4352;
    const float* W;
    f16* Bp;
    int nK32, OCr, K, i;
    bool conv = false;
    if (blk < 2304) {
        W = wk; Bp = bpk; nK32 = 72; OCr = 256; K = 2304; conv = true;
        i = blk * 256 + tid;
    } else if (blk < 4608) {
        W = ws; Bp = bps; nK32 = 72; OCr = 256; K = 2304; conv = true;
        i = (blk - 2304) * 256 + tid;
    } else if (blk < 5376) {  // wd: 16 octs * 24 k32 * 512 = 768 blocks
        W = wd; Bp = bpd; nK32 = 24; OCr = 256; K = 768;
        i = (blk - 4608) * 256 + tid;
    } else if (blk < 5632) {
        W = wh1; Bp = bp1; nK32 = 8; OCr = 256; K = 256;
        i = (blk - 5376) * 256 + tid;
    } else {
        W = wh2; Bp = bp2; nK32 = 8; OCr = 10; K = 256;
        i = (blk - 5632) * 256 + tid;
    }
    int per = nK32 * 512;
    int oct = i / per;
    int r = i - oct * per;
    int k32 = r >> 9;
    int lr = r & 511;
    int l = lr >> 3, j = lr & 7;
    int oc = oct * 16 + (l & 15);
    int k = k32 * 32 + ((l >> 4) << 3) + j;
    float v = 0.f;
    if (oc < OCr)
        v = conv ? W[(size_t)(oc * 256 + (k & 255)) * 9 + (k >> 8)]
                 : W[(size_t)oc * K + k];
    Bp[(size_t)(oct * nK32 + k32) * 512 + lr] = (f16)v;
}

// ---------------------------------------------------------------------------
// 8-phase 256x256 f16 MFMA GEMM (learn_hip m201-style schedule, plain HIP).
//  512 thr = 8 waves (2M x 4N), per-wave 128x64 out (8x4 frags 16x16x32).
//  BK=64; LDS 128KB. See round-1 notes. nKt must be even >= 4.
// ---------------------------------------------------------------------------
template <int KHW, int EPI>
__device__ __forceinline__ void gemm8_body(
    f16* lds, const f16* __restrict__ A, const f16* __restrict__ Bp,
    const float* __restrict__ bnp, float* __restrict__ outF,
    f16* __restrict__ oF, int m0, int M, int OC, int C, int H, int W,
    int OH, int OW) {
    const int Ktot = KHW * C;
    const int nKt = Ktot >> 6;  // 64-wide K tiles (even)
    const int nI = nKt >> 1;
    const int nK32 = Ktot >> 5;
    const int tid = threadIdx.x;
    const int lane = tid & 63;
    const int wid = tid >> 6;   // 0..7
    const int rowl = lane & 15;
    const int quad = lane >> 4;
    const int wm = wid >> 2;    // 0..1 (M)
    const int wn = wid & 3;     // 0..3 (N)
    const int OHW = OH * OW;

    int arow[4];
#pragma unroll
    for (int h = 0; h < 2; ++h)
#pragma unroll
        for (int s = 0; s < 2; ++s) {
            int ml = ((wid & 4) << 5) + h * 64 + (wid & 3) * 16 + s * 8 +
                     (lane >> 3);
            int m = m0 + ml;
            if (m >= M) m = M - 1;
            int b = m / OHW;
            int r = m - b * OHW;
            int y = r / OW;
            int x = r - y * OW;
            arow[h * 2 + s] = ((b * H + y) * W + x) * C +
                              (((lane & 7) ^ (lane >> 3)) << 3);
        }
    int bsrcb[2];
#pragma unroll
    for (int h = 0; h < 2; ++h) {
        int slot = h * 8 + wid;
        int o = ((slot >> 1) & 3) * 4 + ((slot >> 3) << 1) + (slot & 1);
        bsrcb[h] = o * nK32 * 512 + lane * 8;
    }

    auto koff_of = [&](int kt) {
        if (KHW == 9) {
            int pos = kt >> 2;
            int ky = pos / 3, kx = pos - ky * 3;
            return (ky * W + kx) * C + ((kt & 3) << 6);
        }
        return kt << 6;
    };
    auto stageA = [&](int buf, int h, int kt) {
        int koff = koff_of(kt);
#pragma unroll
        for (int s = 0; s < 2; ++s)
            async_copy16(
                &lds[buf * 16384 +
                     ((h * 1024 + wid * 128 + s * 64 + lane) << 3)],
                A + arow[h * 2 + s] + koff);
    };
    auto stageB = [&](int buf, int h, int kt) {
#pragma unroll
        for (int s = 0; s < 2; ++s)
            async_copy16(
                &lds[32768 + buf * 16384 +
                     ((((h * 8 + wid) * 2 + s) * 64 + lane) << 3)],
                Bp + bsrcb[h] + (kt * 2 + s) * 512);
    };

    f32x4 acc[8][4];
#pragma unroll
    for (int i = 0; i < 8; ++i)
#pragma unroll
        for (int j = 0; j < 4; ++j) acc[i][j] = (f32x4)0.f;

    f16x8 ah[4][2], bhA[2][2], bhB[2][2];

    auto dsA = [&](int buf, int qm) {
#pragma unroll
        for (int ii = 0; ii < 4; ++ii) {
            int g = qm * 128 + wm * 64 + ii * 16 + rowl;
#pragma unroll
            for (int ks = 0; ks < 2; ++ks)
                ah[ii][ks] = *(const f16x8*)&lds[
                    buf * 16384 + g * 64 +
                    ((((ks << 2) | quad) ^ (rowl & 7)) << 3)];
        }
    };
    auto dsB = [&](int buf, int qn, f16x8 (&bh)[2][2]) {
#pragma unroll
        for (int jj = 0; jj < 2; ++jj) {
            int slot = qn * 8 + wn * 2 + jj;
#pragma unroll
            for (int ks = 0; ks < 2; ++ks)
                bh[jj][ks] = *(const f16x8*)&lds[
                    32768 + buf * 16384 + (slot * 2 + ks) * 512 + lane * 8];
        }
    };

#define MFMA_QUAD(qm, qn, bh)                                            \
    do {                                                                 \
        _Pragma("unroll") for (int ks = 0; ks < 2; ++ks)                 \
            _Pragma("unroll") for (int ii = 0; ii < 4; ++ii)             \
                _Pragma("unroll") for (int jj = 0; jj < 2; ++jj)         \
                    acc[(qm)*4 + ii][(qn)*2 + jj] =                      \
                        __builtin_amdgcn_mfma_f32_16x16x32_f16(          \
                            ah[ii][ks], bh[jj][ks],                      \
                            acc[(qm)*4 + ii][(qn)*2 + jj], 0, 0, 0);     \
    } while (0)

#define PH_TAIL(MF)                                        \
    __builtin_amdgcn_s_barrier();                          \
    asm volatile("s_waitcnt lgkmcnt(0)" ::: "memory");     \
    __builtin_amdgcn_s_setprio(1);                         \
    MF;                                                    \
    __builtin_amdgcn_s_setprio(0)

    stageA(0, 0, 0);
    stageA(0, 1, 0);
    stageB(0, 0, 0);
    stageB(0, 1, 0);
    stageA(1, 0, 1);
    stageB(1, 0, 1);
    stageB(1, 1, 1);
    asm volatile("s_waitcnt vmcnt(6)" ::: "memory");  // tile0 landed
    __builtin_amdgcn_s_barrier();

    for (int it = 0; it < nI; ++it) {
        const bool more = (it + 1 < nI);
        const int t2 = 2 * it + 2;
        const int t3 = 2 * it + 3;
        dsA(0, 0);
        dsB(0, 0, bhA);
        stageA(1, 1, 2 * it + 1);
        PH_TAIL(MFMA_QUAD(0, 0, bhA));
        __builtin_amdgcn_s_barrier();
        dsB(0, 1, bhB);
        if (more) stageA(0, 0, t2);
        PH_TAIL(MFMA_QUAD(0, 1, bhB));
        __builtin_amdgcn_s_barrier();
        dsA(0, 1);
        if (more) stageB(0, 0, t2);
        PH_TAIL(MFMA_QUAD(1, 0, bhA));
        __builtin_amdgcn_s_barrier();
        if (more) stageB(0, 1, t2);
        PH_TAIL(MFMA_QUAD(1, 1, bhB));
        if (more)
            asm volatile("s_waitcnt vmcnt(6)" ::: "memory");
        else
            asm volatile("s_waitcnt vmcnt(0)" ::: "memory");
        __builtin_amdgcn_s_barrier();
        dsA(1, 0);
        dsB(1, 0, bhA);
        if (more) stageA(0, 1, t2);
        PH_TAIL(MFMA_QUAD(0, 0, bhA));
        __builtin_amdgcn_s_barrier();
        dsB(1, 1, bhB);
        if (more) stageA(1, 0, t3);
        PH_TAIL(MFMA_QUAD(0, 1, bhB));
        __builtin_amdgcn_s_barrier();
        dsA(1, 1);
        if (more) stageB(1, 0, t3);
        PH_TAIL(MFMA_QUAD(1, 0, bhA));
        __builtin_amdgcn_s_barrier();
        if (more) stageB(1, 1, t3);
        PH_TAIL(MFMA_QUAD(1, 1, bhB));
        if (more) asm volatile("s_waitcnt vmcnt(6)" ::: "memory");
        __builtin_amdgcn_s_barrier();
    }
#undef PH_TAIL
#undef MFMA_QUAD

#pragma unroll
    for (int j = 0; j < 4; ++j) {
        int oc = wn * 64 + j * 16 + rowl;
        bool ocv = oc < OC;
        float scale = 1.f, shift = 0.f;
        if (ocv) {
            if (EPI != 3) {
                float g = bnp[oc];
                float bb = bnp[OC + oc];
                float mm = bnp[2 * OC + oc];
                float vv = bnp[3 * OC + oc];
                float inv = g * rsqrtf(vv + EPSBN);
                scale = inv;
                shift = bb - mm * inv;
            } else {
                shift = bnp[oc];  // bias
            }
        }
#pragma unroll
        for (int i = 0; i < 8; ++i) {
#pragma unroll
            for (int r = 0; r < 4; ++r) {
                int m = m0 + wm * 128 + i * 16 + quad * 4 + r;
                if (m < M && ocv) {
                    float v = acc[i][j][r] * scale + shift;
                    if (EPI == 2) v = fmaxf(v, 0.f);
                    if (EPI == 3) {
                        int b = m / OHW;
                        int rr = m - b * OHW;
                        outF[((size_t)b * OC + oc) * OHW + rr] = v;
                    } else {
                        oF[(size_t)m * OC + oc] = (f16)v;
                    }
                }
            }
        }
    }
}

// Fused conv3x3, 8-phase: kernel branch first (blocks [0,7)), search [7,218).
__global__ __launch_bounds__(512, 2) void conv33_fused8(
    const f16* sA_g, const f16* bpS, const float* bns, f16* sOut,
    const f16* kA_g, const f16* bpK, const float* bnk, f16* kOut) {
    __shared__ f16 lds[65536];  // 128 KB
    bool sec = blockIdx.x < 7;
    const f16* A = sec ? kA_g : sA_g;
    const f16* Bp = sec ? bpK : bpS;
    const float* bnp = sec ? bnk : bns;
    f16* oF = sec ? kOut : sOut;
    int M = sec ? 1600 : 53824;
    int Hh = sec ? 7 : 31;
    int OHs = sec ? 5 : 29;
    int m0 = (sec ? blockIdx.x : (blockIdx.x - 7)) * 256;
    gemm8_body<9, 2>(lds, A, Bp, bnp, nullptr, oF, m0, M, 256, 256, Hh, Hh,
                     OHs, OHs);
}

// ---------------------------------------------------------------------------
// Fused pointwise head: feat[40000][768] -> wd/BN -> wh1/BN/ReLU -> wh2+bias
// -> out f32 NCHW.  Row-local chain: per block 80 rows, all intermediates
// stay in LDS (f16, XOR-swizzled [80][256] tile).
//  256 thr = 4 col-waves (each 80x64 out, 5x4 frags 16x16x32 f16).
//  LDS: A-dbuf 2x20KB (stage-1 feat, BK=128) + 40KB f2/h tile = 80KB
//  -> exactly 2 blocks/CU.  500 blocks = 2/CU on 250 CUs, one round.
// ---------------------------------------------------------------------------
__global__ __launch_bounds__(256, 2) void head_fused(
    const f16* __restrict__ feat, const f16* __restrict__ bpd,
    const float* __restrict__ bnd, const f16* __restrict__ bp1,
    const float* __restrict__ bnh, const f16* __restrict__ bp2,
    const float* __restrict__ bh2, float* __restrict__ out) {
    __shared__ f16 lds[40960];  // [0,20480): A dbuf | [20480,40960): f2/h
    const int F2B = 20480;
    const int tid = threadIdx.x;
    const int lane = tid & 63;
    const int rowl = lane & 15;
    const int quad = lane >> 4;
    const int wn = tid >> 6;  // 0..3 column-wave
    const int m0 = blockIdx.x * 80;

    // stage-1 A staging: 1280 chunks = 80 rows x 16 chunks, XOR-swizzled src
    int asrc[5];
#pragma unroll
    for (int s = 0; s < 5; ++s) {
        int idx = tid + s * 256;
        int ml = idx >> 4;
        int qs = (idx & 15) ^ (ml & 15);
        asrc[s] = ml * 768 + qs * 8;
    }
    auto issueA = [&](int buf, int kb) {
#pragma unroll
        for (int s = 0; s < 5; ++s)
            async_copy16(&lds[buf * 10240 + (tid + s * 256) * 8],
                         feat + (size_t)m0 * 768 + asrc[s] + kb * 128);
    };
    auto loadB = [&](f16x8(&bh)[4][4], const f16* __restrict__ Bp, int nK32,
                     int kb) {
#pragma unroll
        for (int ks = 0; ks < 4; ++ks)
#pragma unroll
            for (int j = 0; j < 4; ++j)
                bh[ks][j] = *(const f16x8*)&Bp[((size_t)((wn * 4 + j) * nK32 +
                                                         kb * 4 + ks)) *
                                                   512 +
                                               lane * 8];
    };

    f32x4 acc[5][4];
#pragma unroll
    for (int i = 0; i < 5; ++i)
#pragma unroll
        for (int j = 0; j < 4; ++j) acc[i][j] = (f32x4)0.f;

    auto computeS1 = [&](int buf, f16x8(&bh)[4][4]) {
#pragma unroll
        for (int ks = 0; ks < 4; ++ks) {
            f16x8 ah[5];
#pragma unroll
            for (int i = 0; i < 5; ++i)
                ah[i] = *(const f16x8*)&lds[buf * 10240 +
                                            (i * 16 + rowl) * 128 +
                                            ((((ks << 2) | quad) ^ rowl)
                                             << 3)];
#pragma unroll
            for (int i = 0; i < 5; ++i)
#pragma unroll
                for (int j = 0; j < 4; ++j)
                    acc[i][j] = __builtin_amdgcn_mfma_f32_16x16x32_f16(
                        ah[i], bh[ks][j], acc[i][j], 0, 0, 0);
        }
    };
    // f2/h tile addressing: row stride 256 f16; 3-bit chunk XOR vs row
    auto tileRd = [&](int kb, int ks, int i) {
        int g = i * 16 + rowl;
        int kc = kb * 16 + (ks << 2) + quad;
        int sw = (kc & 24) | ((kc ^ rowl) & 7);
        return *(const f16x8*)&lds[F2B + g * 256 + (sw << 3)];
    };

    // ---- stage 1: wd, K=768 (6 x BK=128, 2-phase dbuf) ----
    f16x8 bh0[4][4], bh1[4][4];
    issueA(0, 0);
    loadB(bh0, bpd, 24, 0);
    for (int kb = 0; kb < 6; kb += 2) {
        __syncthreads();
        issueA(1, kb + 1);
        loadB(bh1, bpd, 24, kb + 1);
        computeS1(0, bh0);
        __syncthreads();
        if (kb + 2 < 6) {
            issueA(0, kb + 2);
            loadB(bh0, bpd, 24, kb + 2);
        }
        computeS1(1, bh1);
    }
    // BN -> f2 tile (no relu)
#pragma unroll
    for (int j = 0; j < 4; ++j) {
        int oc = wn * 64 + j * 16 + rowl;
        float g = bnd[oc], bb = bnd[256 + oc], mm = bnd[512 + oc],
              vv = bnd[768 + oc];
        float inv = g * rsqrtf(vv + EPSBN);
        float shift = bb - mm * inv;
        int c = oc >> 3;
#pragma unroll
        for (int i = 0; i < 5; ++i)
#pragma unroll
            for (int r = 0; r < 4; ++r) {
                int row = i * 16 + quad * 4 + r;
                int sw = (c & 24) | ((c ^ row) & 7);
                lds[F2B + row * 256 + (sw << 3) + (oc & 7)] =
                    (f16)(acc[i][j][r] * inv + shift);
            }
    }
    loadB(bh0, bp1, 8, 0);  // prefetch stage-2 B (overlaps barrier)
    __syncthreads();        // f2 tile complete

    // ---- stage 2: wh1, K=256 (2 x BK=128, A direct from LDS tile) ----
#pragma unroll
    for (int i = 0; i < 5; ++i)
#pragma unroll
        for (int j = 0; j < 4; ++j) acc[i][j] = (f32x4)0.f;
    loadB(bh1, bp1, 8, 1);
#pragma unroll
    for (int kb = 0; kb < 2; ++kb) {
#pragma unroll
        for (int ks = 0; ks < 4; ++ks) {
            f16x8 ah[5];
#pragma unroll
            for (int i = 0; i < 5; ++i) ah[i] = tileRd(kb, ks, i);
#pragma unroll
            for (int i = 0; i < 5; ++i)
#pragma unroll
                for (int j = 0; j < 4; ++j)
                    acc[i][j] = __builtin_amdgcn_mfma_f32_16x16x32_f16(
                        ah[i], kb ? bh1[ks][j] : bh0[ks][j], acc[i][j], 0, 0,
                        0);
        }
    }
    __syncthreads();  // all waves done reading f2 before overwrite
    // BN + ReLU -> h tile (same region/layout)
#pragma unroll
    for (int j = 0; j < 4; ++j) {
        int oc = wn * 64 + j * 16 + rowl;
        float g = bnh[oc], bb = bnh[256 + oc], mm = bnh[512 + oc],
              vv = bnh[768 + oc];
        float inv = g * rsqrtf(vv + EPSBN);
        float shift = bb - mm * inv;
        int c = oc >> 3;
#pragma unroll
        for (int i = 0; i < 5; ++i)
#pragma unroll
            for (int r = 0; r < 4; ++r) {
                int row = i * 16 + quad * 4 + r;
                int sw = (c & 24) | ((c ^ row) & 7);
                lds[F2B + row * 256 + (sw << 3) + (oc & 7)] =
                    (f16)fmaxf(acc[i][j][r] * inv + shift, 0.f);
            }
    }
    __syncthreads();  // h tile complete
    if (wn != 0) return;

    // ---- stage 3: wh2 (OC=10), wave 0 only; ~1.5% of block FLOPs ----
    f32x4 a3[5];
#pragma unroll
    for (int i = 0; i < 5; ++i) a3[i] = (f32x4)0.f;
#pragma unroll
    for (int kb = 0; kb < 2; ++kb)
#pragma unroll
        for (int ks = 0; ks < 4; ++ks) {
            f16x8 b3 =
                *(const f16x8*)&bp2[(size_t)(kb * 4 + ks) * 512 + lane * 8];
#pragma unroll
            for (int i = 0; i < 5; ++i)
                a3[i] = __builtin_amdgcn_mfma_f32_16x16x32_f16(
                    tileRd(kb, ks, i), b3, a3[i], 0, 0, 0);
        }
    int oc = rowl;
    if (oc < 10) {
        float shift = bh2[oc];
#pragma unroll
        for (int i = 0; i < 5; ++i)
#pragma unroll
            for (int r = 0; r < 4; ++r) {
                int m = m0 + i * 16 + quad * 4 + r;
                int b = m / 625;
                int rr = m - b * 625;
                out[((size_t)b * 10 + oc) * 625 + rr] = a3[i][r] + shift;
            }
    }
}

// ---------------------------------------------------------------------------
// Multi-scale depthwise xcorr, NHWC f16 in, f16 NHWC out (f32 accumulate).
// ---------------------------------------------------------------------------
__global__ __launch_bounds__(256) void xcorr_nhwc(
    const f16* __restrict__ sf, const f16* __restrict__ kf,
    f16* __restrict__ feat) {
    int by = blockIdx.x;  // b*25 + y
    int b = by / 25;
    int y = by - b * 25;
    int c = threadIdx.x;  // 0..255
    float kv[25];
#pragma unroll
    for (int p = 0; p < 25; ++p)
        kv[p] = (float)kf[(size_t)(b * 25 + p) * 256 + c];
    const f16* srow = sf + (size_t)(b * 29 + y) * 29 * 256 + c;
    float sv[25];
#pragma unroll
    for (int d = 0; d < 5; ++d)
#pragma unroll
        for (int e = 0; e < 5; ++e)
            sv[d * 5 + e] = (float)srow[(size_t)(d * 29 + e) * 256];
    for (int x = 0;; ++x) {
        float a0 = 0.f, a1 = 0.f, a2;
#pragma unroll
        for (int p = 0; p < 25; ++p) a0 = fmaf(sv[p], kv[p], a0);
#pragma unroll
        for (int d = 1; d < 4; ++d)
#pragma unroll
            for (int e = 1; e < 4; ++e)
                a1 = fmaf(sv[d * 5 + e], kv[d * 5 + e], a1);
        a2 = sv[12] * kv[12];
        size_t o = ((size_t)by * 25 + x) * 768 + c;
        feat[o] = (f16)a0;
        feat[o + 256] = (f16)a1;
        feat[o + 512] = (f16)a2;
        if (x == 24) break;
#pragma unroll
        for (int d = 0; d < 5; ++d) {
#pragma unroll
            for (int e = 0; e < 4; ++e) sv[d * 5 + e] = sv[d * 5 + e + 1];
            sv[d * 5 + 4] = (float)srow[(size_t)(d * 29 + x + 5) * 256];
        }
    }
}

// ---------------------------------------------------------------------------
extern "C" void kernel_launch(void* const* d_in, const int* in_sizes, int n_in,
                              void* d_out, int out_size, void* d_ws,
                              size_t ws_size, hipStream_t stream) {
    const float* kernel_in = (const float*)d_in[0];  // (64,256,7,7)
    const float* search_in = (const float*)d_in[1];  // (64,256,31,31)
    const float* wk = (const float*)d_in[2];         // (256,256,3,3)
    const float* bnk = (const float*)d_in[3];
    const float* ws = (const float*)d_in[4];
    const float* bns = (const float*)d_in[5];
    const float* wd = (const float*)d_in[6];  // (256,768)
    const float* bnd = (const float*)d_in[7];
    const float* wh1 = (const float*)d_in[8];  // (256,256)
    const float* bnh = (const float*)d_in[9];
    const float* wh2 = (const float*)d_in[10];  // (10,256)
    const float* bh2 = (const float*)d_in[11];  // (10,)
    float* out = (float*)d_out;                 // (64,10,25,25) NCHW

    char* base = (char*)d_ws;
    size_t off = 0;
    auto alloc = [&](size_t bytes) {
        off = (off + 511) & ~(size_t)511;
        void* p = base + off;
        off += bytes;
        return p;
    };

    // Persistent region
    f16* bpd = (f16*)alloc((size_t)16 * 24 * 512 * 2);  // wd frags
    f16* bp1 = (f16*)alloc((size_t)16 * 8 * 512 * 2);   // wh1 frags
    f16* bp2 = (f16*)alloc((size_t)8 * 8 * 512 * 2);    // wh2 frags (padded)
    f16* kfeat = (f16*)alloc((size_t)1600 * 256 * 2);
    f16* sfeat = (f16*)alloc((size_t)53824 * 256 * 2);
    size_t P1 = (off + 511) & ~(size_t)511;  // feat aliases here
    // Transients (dead after conv33_fused8)
    f16* bpk = (f16*)alloc((size_t)16 * 72 * 512 * 2);
    f16* bps = (f16*)alloc((size_t)16 * 72 * 512 * 2);
    f16* ka = (f16*)alloc((size_t)64 * 49 * 256 * 2);
    f16* sa = (f16*)alloc((size_t)64 * 961 * 256 * 2);
    // Alias: feat over dead transients + free space
    f16* feat = (f16*)(base + P1);  // 40000*768 f16

    // 1) activation transpose->f16 NHWC + all weight fragment packs
    prep_all<<<dim3(10112), 256, 0, stream>>>(search_in, sa, kernel_in, ka,
                                              wk, ws, wd, wh1, wh2, bpk, bps,
                                              bpd, bp1, bp2);
    // 2) fused conv3x3 (kernel + search), 8-phase 256^2 -> f16 NHWC
    conv33_fused8<<<dim3(218), 512, 0, stream>>>(sa, bps, bns, sfeat, ka,
                                                 bpk, bnk, kfeat);
    // 3) xcorr -> feat f16 NHWC [40000][768]
    xcorr_nhwc<<<dim3(1600), 256, 0, stream>>>(sfeat, kfeat, feat);
    // 4-6) fused pointwise head: wd/BN -> wh1/BN/ReLU -> wh2+bias -> out
    head_fused<<<dim3(500), 256, 0, stream>>>(feat, bpd, bnd, bp1, bnh, bp2,
                                              bh2, out);
}

// Round 4
// 268.950 us; speedup vs baseline: 1.2237x; 1.0163x over previous
//
#include <hip/hip_runtime.h>
#include <hip/hip_bf16.h>
#include <cstdint>
#include <cstddef>

#define EPSBN 1e-5f

typedef unsigned short u16;
typedef unsigned int u32;
typedef _Float16 f16;
typedef _Float16 f16x8 __attribute__((ext_vector_type(8)));
typedef float f32x4 __attribute__((ext_vector_type(4)));

// async global->LDS, 16B per lane
__device__ __forceinline__ void async_copy16(void* lds, const void* g) {
    __builtin_amdgcn_global_load_lds(
        (const __attribute__((address_space(1))) u32*)g,
        (__attribute__((address_space(3))) u32*)lds, 16, 0, 0);
}

// ---------------------------------------------------------------------------
// One prep kernel:
//  blocks [0,4352): NCHW f32 -> NHWC f16 transpose (search + kernel acts)
//  blocks [4352,...): weight fragment packing, f16:
//    Bp[oct][k32][lane][j] = W[oct*16+(lane&15)][k32*32+(lane>>4)*8+j]
//    3x3 convs use k = pos*256+cin (matches A im2col order).
//    ranges (blocks): wk 2304 | ws 2304 | wd 768 | wh1 256 | wh2 128
// ---------------------------------------------------------------------------
__global__ __launch_bounds__(256) void prep_all(
    const float* __restrict__ sin, f16* __restrict__ sa,
    const float* __restrict__ kin, f16* __restrict__ ka,
    const float* __restrict__ wk, const float* __restrict__ ws,
    const float* __restrict__ wd, const float* __restrict__ wh1,
    const float* __restrict__ wh2, f16* __restrict__ bpk,
    f16* __restrict__ bps, f16* __restrict__ bpd, f16* __restrict__ bp1,
    f16* __restrict__ bp2) {
    __shared__ float tile[64][65];
    int t = blockIdx.x;
    int tid = threadIdx.x;
    if (t < 4352) {  // 64 b x 4 ctiles x 17 z
        int b = t / 68;
        int rem = t - b * 68;
        int c0 = (rem / 17) * 64;
        int z = rem % 17;
        bool isk = (z == 16);
        const float* in = isk ? kin : sin;
        f16* op = isk ? ka : sa;
        int HW = isk ? 49 : 961;
        int h0 = isk ? 0 : z * 64;
        int cl = tid >> 6;
        int hl = tid & 63;
        for (int r = cl; r < 64; r += 4) {
            int hw = h0 + hl;
            tile[r][hl] =
                (hw < HW) ? in[(size_t)(b * 256 + c0 + r) * HW + hw] : 0.f;
        }
        __syncthreads();
        int c = tid & 63;
        for (int r = cl; r < 64; r += 4) {
            int hw = h0 + r;
            if (hw < HW)
                op[((size_t)b * HW + hw) * 256 + c0 + c] = (f16)tile[c][r];
        }
        return;
    }
    int blk = t - 4352;
    const float* W;
    f16* Bp;
    int nK32, OCr, K, i;
    bool conv = false;
    if (blk < 2304) {
        W = wk; Bp = bpk; nK32 = 72; OCr = 256; K = 2304; conv = true;
        i = blk * 256 + tid;
    } else if (blk < 4608) {
        W = ws; Bp = bps; nK32 = 72; OCr = 256; K = 2304; conv = true;
        i = (blk - 2304) * 256 + tid;
    } else if (blk < 5376) {  // wd: 16 octs * 24 k32 * 512 = 768 blocks
        W = wd; Bp = bpd; nK32 = 24; OCr = 256; K = 768;
        i = (blk - 4608) * 256 + tid;
    } else if (blk < 5632) {
        W = wh1; Bp = bp1; nK32 = 8; OCr = 256; K = 256;
        i = (blk - 5376) * 256 + tid;
    } else {
        W = wh2; Bp = bp2; nK32 = 8; OCr = 10; K = 256;
        i = (blk - 5632) * 256 + tid;
    }
    int per = nK32 * 512;
    int oct = i / per;
    int r = i - oct * per;
    int k32 = r >> 9;
    int lr = r & 511;
    int l = lr >> 3, j = lr & 7;
    int oc = oct * 16 + (l & 15);
    int k = k32 * 32 + ((l >> 4) << 3) + j;
    float v = 0.f;
    if (oc < OCr)
        v = conv ? W[(size_t)(oc * 256 + (k & 255)) * 9 + (k >> 8)]
                 : W[(size_t)oc * K + k];
    Bp[(size_t)(oct * nK32 + k32) * 512 + lr] = (f16)v;
}

// ---------------------------------------------------------------------------
// 8-phase 256x256 f16 MFMA GEMM (learn_hip m201-style schedule, plain HIP).
//  512 thr = 8 waves (2M x 4N), per-wave 128x64 out (8x4 frags 16x16x32).
//  BK=64; LDS 128KB. See round-1 notes. nKt must be even >= 4.
// ---------------------------------------------------------------------------
template <int KHW, int EPI>
__device__ __forceinline__ void gemm8_body(
    f16* lds, const f16* __restrict__ A, const f16* __restrict__ Bp,
    const float* __restrict__ bnp, float* __restrict__ outF,
    f16* __restrict__ oF, int m0, int M, int OC, int C, int H, int W,
    int OH, int OW) {
    const int Ktot = KHW * C;
    const int nKt = Ktot >> 6;  // 64-wide K tiles (even)
    const int nI = nKt >> 1;
    const int nK32 = Ktot >> 5;
    const int tid = threadIdx.x;
    const int lane = tid & 63;
    const int wid = tid >> 6;   // 0..7
    const int rowl = lane & 15;
    const int quad = lane >> 4;
    const int wm = wid >> 2;    // 0..1 (M)
    const int wn = wid & 3;     // 0..3 (N)
    const int OHW = OH * OW;

    int arow[4];
#pragma unroll
    for (int h = 0; h < 2; ++h)
#pragma unroll
        for (int s = 0; s < 2; ++s) {
            int ml = ((wid & 4) << 5) + h * 64 + (wid & 3) * 16 + s * 8 +
                     (lane >> 3);
            int m = m0 + ml;
            if (m >= M) m = M - 1;
            int b = m / OHW;
            int r = m - b * OHW;
            int y = r / OW;
            int x = r - y * OW;
            arow[h * 2 + s] = ((b * H + y) * W + x) * C +
                              (((lane & 7) ^ (lane >> 3)) << 3);
        }
    int bsrcb[2];
#pragma unroll
    for (int h = 0; h < 2; ++h) {
        int slot = h * 8 + wid;
        int o = ((slot >> 1) & 3) * 4 + ((slot >> 3) << 1) + (slot & 1);
        bsrcb[h] = o * nK32 * 512 + lane * 8;
    }

    auto koff_of = [&](int kt) {
        if (KHW == 9) {
            int pos = kt >> 2;
            int ky = pos / 3, kx = pos - ky * 3;
            return (ky * W + kx) * C + ((kt & 3) << 6);
        }
        return kt << 6;
    };
    auto stageA = [&](int buf, int h, int kt) {
        int koff = koff_of(kt);
#pragma unroll
        for (int s = 0; s < 2; ++s)
            async_copy16(
                &lds[buf * 16384 +
                     ((h * 1024 + wid * 128 + s * 64 + lane) << 3)],
                A + arow[h * 2 + s] + koff);
    };
    auto stageB = [&](int buf, int h, int kt) {
#pragma unroll
        for (int s = 0; s < 2; ++s)
            async_copy16(
                &lds[32768 + buf * 16384 +
                     ((((h * 8 + wid) * 2 + s) * 64 + lane) << 3)],
                Bp + bsrcb[h] + (kt * 2 + s) * 512);
    };

    f32x4 acc[8][4];
#pragma unroll
    for (int i = 0; i < 8; ++i)
#pragma unroll
        for (int j = 0; j < 4; ++j) acc[i][j] = (f32x4)0.f;

    f16x8 ah[4][2], bhA[2][2], bhB[2][2];

    auto dsA = [&](int buf, int qm) {
#pragma unroll
        for (int ii = 0; ii < 4; ++ii) {
            int g = qm * 128 + wm * 64 + ii * 16 + rowl;
#pragma unroll
            for (int ks = 0; ks < 2; ++ks)
                ah[ii][ks] = *(const f16x8*)&lds[
                    buf * 16384 + g * 64 +
                    ((((ks << 2) | quad) ^ (rowl & 7)) << 3)];
        }
    };
    auto dsB = [&](int buf, int qn, f16x8 (&bh)[2][2]) {
#pragma unroll
        for (int jj = 0; jj < 2; ++jj) {
            int slot = qn * 8 + wn * 2 + jj;
#pragma unroll
            for (int ks = 0; ks < 2; ++ks)
                bh[jj][ks] = *(const f16x8*)&lds[
                    32768 + buf * 16384 + (slot * 2 + ks) * 512 + lane * 8];
        }
    };

#define MFMA_QUAD(qm, qn, bh)                                            \
    do {                                                                 \
        _Pragma("unroll") for (int ks = 0; ks < 2; ++ks)                 \
            _Pragma("unroll") for (int ii = 0; ii < 4; ++ii)             \
                _Pragma("unroll") for (int jj = 0; jj < 2; ++jj)         \
                    acc[(qm)*4 + ii][(qn)*2 + jj] =                      \
                        __builtin_amdgcn_mfma_f32_16x16x32_f16(          \
                            ah[ii][ks], bh[jj][ks],                      \
                            acc[(qm)*4 + ii][(qn)*2 + jj], 0, 0, 0);     \
    } while (0)

#define PH_TAIL(MF)                                        \
    __builtin_amdgcn_s_barrier();                          \
    asm volatile("s_waitcnt lgkmcnt(0)" ::: "memory");     \
    __builtin_amdgcn_s_setprio(1);                         \
    MF;                                                    \
    __builtin_amdgcn_s_setprio(0)

    stageA(0, 0, 0);
    stageA(0, 1, 0);
    stageB(0, 0, 0);
    stageB(0, 1, 0);
    stageA(1, 0, 1);
    stageB(1, 0, 1);
    stageB(1, 1, 1);
    asm volatile("s_waitcnt vmcnt(6)" ::: "memory");  // tile0 landed
    __builtin_amdgcn_s_barrier();

    for (int it = 0; it < nI; ++it) {
        const bool more = (it + 1 < nI);
        const int t2 = 2 * it + 2;
        const int t3 = 2 * it + 3;
        dsA(0, 0);
        dsB(0, 0, bhA);
        stageA(1, 1, 2 * it + 1);
        PH_TAIL(MFMA_QUAD(0, 0, bhA));
        __builtin_amdgcn_s_barrier();
        dsB(0, 1, bhB);
        if (more) stageA(0, 0, t2);
        PH_TAIL(MFMA_QUAD(0, 1, bhB));
        __builtin_amdgcn_s_barrier();
        dsA(0, 1);
        if (more) stageB(0, 0, t2);
        PH_TAIL(MFMA_QUAD(1, 0, bhA));
        __builtin_amdgcn_s_barrier();
        if (more) stageB(0, 1, t2);
        PH_TAIL(MFMA_QUAD(1, 1, bhB));
        if (more)
            asm volatile("s_waitcnt vmcnt(6)" ::: "memory");
        else
            asm volatile("s_waitcnt vmcnt(0)" ::: "memory");
        __builtin_amdgcn_s_barrier();
        dsA(1, 0);
        dsB(1, 0, bhA);
        if (more) stageA(0, 1, t2);
        PH_TAIL(MFMA_QUAD(0, 0, bhA));
        __builtin_amdgcn_s_barrier();
        dsB(1, 1, bhB);
        if (more) stageA(1, 0, t3);
        PH_TAIL(MFMA_QUAD(0, 1, bhB));
        __builtin_amdgcn_s_barrier();
        dsA(1, 1);
        if (more) stageB(1, 0, t3);
        PH_TAIL(MFMA_QUAD(1, 0, bhA));
        __builtin_amdgcn_s_barrier();
        if (more) stageB(1, 1, t3);
        PH_TAIL(MFMA_QUAD(1, 1, bhB));
        if (more) asm volatile("s_waitcnt vmcnt(6)" ::: "memory");
        __builtin_amdgcn_s_barrier();
    }
#undef PH_TAIL
#undef MFMA_QUAD

#pragma unroll
    for (int j = 0; j < 4; ++j) {
        int oc = wn * 64 + j * 16 + rowl;
        bool ocv = oc < OC;
        float scale = 1.f, shift = 0.f;
        if (ocv) {
            if (EPI != 3) {
                float g = bnp[oc];
                float bb = bnp[OC + oc];
                float mm = bnp[2 * OC + oc];
                float vv = bnp[3 * OC + oc];
                float inv = g * rsqrtf(vv + EPSBN);
                scale = inv;
                shift = bb - mm * inv;
            } else {
                shift = bnp[oc];  // bias
            }
        }
#pragma unroll
        for (int i = 0; i < 8; ++i) {
#pragma unroll
            for (int r = 0; r < 4; ++r) {
                int m = m0 + wm * 128 + i * 16 + quad * 4 + r;
                if (m < M && ocv) {
                    float v = acc[i][j][r] * scale + shift;
                    if (EPI == 2) v = fmaxf(v, 0.f);
                    if (EPI == 3) {
                        int b = m / OHW;
                        int rr = m - b * OHW;
                        outF[((size_t)b * OC + oc) * OHW + rr] = v;
                    } else {
                        oF[(size_t)m * OC + oc] = (f16)v;
                    }
                }
            }
        }
    }
}

// Fused conv3x3, 8-phase: kernel branch first (blocks [0,7)), search [7,218).
__global__ __launch_bounds__(512, 2) void conv33_fused8(
    const f16* sA_g, const f16* bpS, const float* bns, f16* sOut,
    const f16* kA_g, const f16* bpK, const float* bnk, f16* kOut) {
    __shared__ f16 lds[65536];  // 128 KB
    bool sec = blockIdx.x < 7;
    const f16* A = sec ? kA_g : sA_g;
    const f16* Bp = sec ? bpK : bpS;
    const float* bnp = sec ? bnk : bns;
    f16* oF = sec ? kOut : sOut;
    int M = sec ? 1600 : 53824;
    int Hh = sec ? 7 : 31;
    int OHs = sec ? 5 : 29;
    int m0 = (sec ? blockIdx.x : (blockIdx.x - 7)) * 256;
    gemm8_body<9, 2>(lds, A, Bp, bnp, nullptr, oF, m0, M, 256, 256, Hh, Hh,
                     OHs, OHs);
}

// ---------------------------------------------------------------------------
// Fused pointwise head: feat[40000][768] -> wd/BN -> wh1/BN/ReLU -> wh2+bias
// -> out f32 NCHW.  Row-local chain: per block 80 rows, all intermediates
// stay in LDS (f16, XOR-swizzled [80][256] tile).
//  256 thr = 4 col-waves (each 80x64 out, 5x4 frags 16x16x32 f16).
//  LDS: A-dbuf 2x20KB (stage-1 feat, BK=128) + 40KB f2/h tile = 80KB
//  -> exactly 2 blocks/CU.  500 blocks = 2/CU on 250 CUs, one round.
// ---------------------------------------------------------------------------
__global__ __launch_bounds__(256, 2) void head_fused(
    const f16* __restrict__ feat, const f16* __restrict__ bpd,
    const float* __restrict__ bnd, const f16* __restrict__ bp1,
    const float* __restrict__ bnh, const f16* __restrict__ bp2,
    const float* __restrict__ bh2, float* __restrict__ out) {
    __shared__ f16 lds[40960];  // [0,20480): A dbuf | [20480,40960): f2/h
    const int F2B = 20480;
    const int tid = threadIdx.x;
    const int lane = tid & 63;
    const int rowl = lane & 15;
    const int quad = lane >> 4;
    const int wn = tid >> 6;  // 0..3 column-wave
    const int m0 = blockIdx.x * 80;

    // stage-1 A staging: 1280 chunks = 80 rows x 16 chunks, XOR-swizzled src
    int asrc[5];
#pragma unroll
    for (int s = 0; s < 5; ++s) {
        int idx = tid + s * 256;
        int ml = idx >> 4;
        int qs = (idx & 15) ^ (ml & 15);
        asrc[s] = ml * 768 + qs * 8;
    }
    auto issueA = [&](int buf, int kb) {
#pragma unroll
        for (int s = 0; s < 5; ++s)
            async_copy16(&lds[buf * 10240 + (tid + s * 256) * 8],
                         feat + (size_t)m0 * 768 + asrc[s] + kb * 128);
    };
    auto loadB = [&](f16x8(&bh)[4][4], const f16* __restrict__ Bp, int nK32,
                     int kb) {
#pragma unroll
        for (int ks = 0; ks < 4; ++ks)
#pragma unroll
            for (int j = 0; j < 4; ++j)
                bh[ks][j] = *(const f16x8*)&Bp[((size_t)((wn * 4 + j) * nK32 +
                                                         kb * 4 + ks)) *
                                                   512 +
                                               lane * 8];
    };

    f32x4 acc[5][4];
#pragma unroll
    for (int i = 0; i < 5; ++i)
#pragma unroll
        for (int j = 0; j < 4; ++j) acc[i][j] = (f32x4)0.f;

    auto computeS1 = [&](int buf, f16x8(&bh)[4][4]) {
#pragma unroll
        for (int ks = 0; ks < 4; ++ks) {
            f16x8 ah[5];
#pragma unroll
            for (int i = 0; i < 5; ++i)
                ah[i] = *(const f16x8*)&lds[buf * 10240 +
                                            (i * 16 + rowl) * 128 +
                                            ((((ks << 2) | quad) ^ rowl)
                                             << 3)];
#pragma unroll
            for (int i = 0; i < 5; ++i)
#pragma unroll
                for (int j = 0; j < 4; ++j)
                    acc[i][j] = __builtin_amdgcn_mfma_f32_16x16x32_f16(
                        ah[i], bh[ks][j], acc[i][j], 0, 0, 0);
        }
    };
    // f2/h tile addressing: row stride 256 f16; 3-bit chunk XOR vs row
    auto tileRd = [&](int kb, int ks, int i) {
        int g = i * 16 + rowl;
        int kc = kb * 16 + (ks << 2) + quad;
        int sw = (kc & 24) | ((kc ^ rowl) & 7);
        return *(const f16x8*)&lds[F2B + g * 256 + (sw << 3)];
    };

    // ---- stage 1: wd, K=768 (6 x BK=128, 2-phase dbuf) ----
    f16x8 bh0[4][4], bh1[4][4];
    issueA(0, 0);
    loadB(bh0, bpd, 24, 0);
    for (int kb = 0; kb < 6; kb += 2) {
        __syncthreads();
        issueA(1, kb + 1);
        loadB(bh1, bpd, 24, kb + 1);
        computeS1(0, bh0);
        __syncthreads();
        if (kb + 2 < 6) {
            issueA(0, kb + 2);
            loadB(bh0, bpd, 24, kb + 2);
        }
        computeS1(1, bh1);
    }
    // BN -> f2 tile (no relu)
#pragma unroll
    for (int j = 0; j < 4; ++j) {
        int oc = wn * 64 + j * 16 + rowl;
        float g = bnd[oc], bb = bnd[256 + oc], mm = bnd[512 + oc],
              vv = bnd[768 + oc];
        float inv = g * rsqrtf(vv + EPSBN);
        float shift = bb - mm * inv;
        int c = oc >> 3;
#pragma unroll
        for (int i = 0; i < 5; ++i)
#pragma unroll
            for (int r = 0; r < 4; ++r) {
                int row = i * 16 + quad * 4 + r;
                int sw = (c & 24) | ((c ^ row) & 7);
                lds[F2B + row * 256 + (sw << 3) + (oc & 7)] =
                    (f16)(acc[i][j][r] * inv + shift);
            }
    }
    loadB(bh0, bp1, 8, 0);  // prefetch stage-2 B (overlaps barrier)
    __syncthreads();        // f2 tile complete

    // ---- stage 2: wh1, K=256 (2 x BK=128, A direct from LDS tile) ----
#pragma unroll
    for (int i = 0; i < 5; ++i)
#pragma unroll
        for (int j = 0; j < 4; ++j) acc[i][j] = (f32x4)0.f;
    loadB(bh1, bp1, 8, 1);
#pragma unroll
    for (int kb = 0; kb < 2; ++kb) {
#pragma unroll
        for (int ks = 0; ks < 4; ++ks) {
            f16x8 ah[5];
#pragma unroll
            for (int i = 0; i < 5; ++i) ah[i] = tileRd(kb, ks, i);
#pragma unroll
            for (int i = 0; i < 5; ++i)
#pragma unroll
                for (int j = 0; j < 4; ++j)
                    acc[i][j] = __builtin_amdgcn_mfma_f32_16x16x32_f16(
                        ah[i], kb ? bh1[ks][j] : bh0[ks][j], acc[i][j], 0, 0,
                        0);
        }
    }
    __syncthreads();  // all waves done reading f2 before overwrite
    // BN + ReLU -> h tile (same region/layout)
#pragma unroll
    for (int j = 0; j < 4; ++j) {
        int oc = wn * 64 + j * 16 + rowl;
        float g = bnh[oc], bb = bnh[256 + oc], mm = bnh[512 + oc],
              vv = bnh[768 + oc];
        float inv = g * rsqrtf(vv + EPSBN);
        float shift = bb - mm * inv;
        int c = oc >> 3;
#pragma unroll
        for (int i = 0; i < 5; ++i)
#pragma unroll
            for (int r = 0; r < 4; ++r) {
                int row = i * 16 + quad * 4 + r;
                int sw = (c & 24) | ((c ^ row) & 7);
                lds[F2B + row * 256 + (sw << 3) + (oc & 7)] =
                    (f16)fmaxf(acc[i][j][r] * inv + shift, 0.f);
            }
    }
    __syncthreads();  // h tile complete
    if (wn != 0) return;

    // ---- stage 3: wh2 (OC=10), wave 0 only; ~1.5% of block FLOPs ----
    f32x4 a3[5];
#pragma unroll
    for (int i = 0; i < 5; ++i) a3[i] = (f32x4)0.f;
#pragma unroll
    for (int kb = 0; kb < 2; ++kb)
#pragma unroll
        for (int ks = 0; ks < 4; ++ks) {
            f16x8 b3 =
                *(const f16x8*)&bp2[(size_t)(kb * 4 + ks) * 512 + lane * 8];
#pragma unroll
            for (int i = 0; i < 5; ++i)
                a3[i] = __builtin_amdgcn_mfma_f32_16x16x32_f16(
                    tileRd(kb, ks, i), b3, a3[i], 0, 0, 0);
        }
    int oc = rowl;
    if (oc < 10) {
        float shift = bh2[oc];
#pragma unroll
        for (int i = 0; i < 5; ++i)
#pragma unroll
            for (int r = 0; r < 4; ++r) {
                int m = m0 + i * 16 + quad * 4 + r;
                int b = m / 625;
                int rr = m - b * 625;
                out[((size_t)b * 10 + oc) * 625 + rr] = a3[i][r] + shift;
            }
    }
}

// ---------------------------------------------------------------------------
// Multi-scale depthwise xcorr, NHWC f16 in, f16 NHWC out (f32 accumulate).
// Fully unrolled sliding window: shifts become SSA renames, cross-x ILP
// breaks the 25-deep fma dependency chain, loads hoist early.
// Chained sums: a2 (center) -> a1 (+8 inner) -> a0 (+16 border): 25 fma/x.
// ---------------------------------------------------------------------------
__global__ __launch_bounds__(256) void xcorr_nhwc(
    const f16* __restrict__ sf, const f16* __restrict__ kf,
    f16* __restrict__ feat) {
    int by = blockIdx.x;  // b*25 + y
    int b = by / 25;
    int y = by - b * 25;
    int c = threadIdx.x;  // 0..255
    float kv[25];
#pragma unroll
    for (int p = 0; p < 25; ++p)
        kv[p] = (float)kf[(size_t)(b * 25 + p) * 256 + c];
    const f16* srow = sf + (size_t)(b * 29 + y) * 29 * 256 + c;
    float sv[25];
#pragma unroll
    for (int d = 0; d < 5; ++d)
#pragma unroll
        for (int e = 0; e < 5; ++e)
            sv[d * 5 + e] = (float)srow[(size_t)(d * 29 + e) * 256];
#pragma unroll
    for (int x = 0; x < 25; ++x) {
        float a2 = sv[12] * kv[12];
        float a1 = a2;
#pragma unroll
        for (int d = 1; d < 4; ++d)
#pragma unroll
            for (int e = 1; e < 4; ++e)
                if (d != 2 || e != 2)
                    a1 = fmaf(sv[d * 5 + e], kv[d * 5 + e], a1);
        float a0 = a1;
#pragma unroll
        for (int p = 0; p < 25; ++p) {
            int d = p / 5, e = p % 5;
            if (d == 0 || d == 4 || e == 0 || e == 4)
                a0 = fmaf(sv[p], kv[p], a0);
        }
        size_t o = ((size_t)by * 25 + x) * 768 + c;
        feat[o] = (f16)a0;
        feat[o + 256] = (f16)a1;
        feat[o + 512] = (f16)a2;
        if (x < 24) {
#pragma unroll
            for (int d = 0; d < 5; ++d) {
#pragma unroll
                for (int e = 0; e < 4; ++e) sv[d * 5 + e] = sv[d * 5 + e + 1];
                sv[d * 5 + 4] = (float)srow[(size_t)(d * 29 + x + 5) * 256];
            }
        }
    }
}

// ---------------------------------------------------------------------------
extern "C" void kernel_launch(void* const* d_in, const int* in_sizes, int n_in,
                              void* d_out, int out_size, void* d_ws,
                              size_t ws_size, hipStream_t stream) {
    const float* kernel_in = (const float*)d_in[0];  // (64,256,7,7)
    const float* search_in = (const float*)d_in[1];  // (64,256,31,31)
    const float* wk = (const float*)d_in[2];         // (256,256,3,3)
    const float* bnk = (const float*)d_in[3];
    const float* ws = (const float*)d_in[4];
    const float* bns = (const float*)d_in[5];
    const float* wd = (const float*)d_in[6];  // (256,768)
    const float* bnd = (const float*)d_in[7];
    const float* wh1 = (const float*)d_in[8];  // (256,256)
    const float* bnh = (const float*)d_in[9];
    const float* wh2 = (const float*)d_in[10];  // (10,256)
    const float* bh2 = (const float*)d_in[11];  // (10,)
    float* out = (float*)d_out;                 // (64,10,25,25) NCHW

    char* base = (char*)d_ws;
    size_t off = 0;
    auto alloc = [&](size_t bytes) {
        off = (off + 511) & ~(size_t)511;
        void* p = base + off;
        off += bytes;
        return p;
    };

    // Persistent region
    f16* bpd = (f16*)alloc((size_t)16 * 24 * 512 * 2);  // wd frags
    f16* bp1 = (f16*)alloc((size_t)16 * 8 * 512 * 2);   // wh1 frags
    f16* bp2 = (f16*)alloc((size_t)8 * 8 * 512 * 2);    // wh2 frags (padded)
    f16* kfeat = (f16*)alloc((size_t)1600 * 256 * 2);
    f16* sfeat = (f16*)alloc((size_t)53824 * 256 * 2);
    size_t P1 = (off + 511) & ~(size_t)511;  // feat aliases here
    // Transients (dead after conv33_fused8)
    f16* bpk = (f16*)alloc((size_t)16 * 72 * 512 * 2);
    f16* bps = (f16*)alloc((size_t)16 * 72 * 512 * 2);
    f16* ka = (f16*)alloc((size_t)64 * 49 * 256 * 2);
    f16* sa = (f16*)alloc((size_t)64 * 961 * 256 * 2);
    // Alias: feat over dead transients + free space
    f16* feat = (f16*)(base + P1);  // 40000*768 f16

    // 1) activation transpose->f16 NHWC + all weight fragment packs
    prep_all<<<dim3(10112), 256, 0, stream>>>(search_in, sa, kernel_in, ka,
                                              wk, ws, wd, wh1, wh2, bpk, bps,
                                              bpd, bp1, bp2);
    // 2) fused conv3x3 (kernel + search), 8-phase 256^2 -> f16 NHWC
    conv33_fused8<<<dim3(218), 512, 0, stream>>>(sa, bps, bns, sfeat, ka,
                                                 bpk, bnk, kfeat);
    // 3) xcorr -> feat f16 NHWC [40000][768]
    xcorr_nhwc<<<dim3(1600), 256, 0, stream>>>(sfeat, kfeat, feat);
    // 4-6) fused pointwise head: wd/BN -> wh1/BN/ReLU -> wh2+bias -> out
    head_fused<<<dim3(500), 256, 0, stream>>>(feat, bpd, bnd, bp1, bnh, bp2,
                                              bh2, out);
}